// Round 16
// baseline (49.539 us; speedup 1.0000x reference)
//
#include <hip/hip_runtime.h>
#include <math.h>

#define DV   256      // d_model
#define BB   64       // batch
#define LL   512      // seq len
#define DEG2 16       // 2 * n_degree
#define VV   8000     // vocab
#define CC   4        // n_category
#define LPW  4        // l's per wave-item
#define NQ   (LL/LPW) // 128 l-quads per batch
#define NE   (BB*LL*DEG2)   // 524288 edges
#define LN_EPS 1e-5f

typedef _Float16 half4 __attribute__((ext_vector_type(4)));
typedef float    f32x4 __attribute__((ext_vector_type(4)));

// ---------------- Kernel 1: LN the table -> fp16 [VV][64 chunks of 8B], + we_flat gather ----------------
__global__ void __launch_bounds__(64) ln_rows_kernel(
    const float* __restrict__ emb, const float* __restrict__ gamma,
    const float* __restrict__ beta,
    const int* __restrict__ w_edge, const float* __restrict__ we_table,
    half4* __restrict__ out, float* __restrict__ we_flat)
{
    const int row = blockIdx.x;
    const int ln  = threadIdx.x;

    // random we_table gather amortized across the grid (latency hides under LN)
    for (int g = blockIdx.x * 64 + ln; g < NE; g += VV * 64)
        we_flat[g] = we_table[w_edge[g]];

    const f32x4 v = ((const f32x4*)(emb + row * DV))[ln];

    float s = v[0] + v[1] + v[2] + v[3];
    #pragma unroll
    for (int off = 32; off > 0; off >>= 1) s += __shfl_xor(s, off);
    const float mu = s * (1.0f / DV);

    f32x4 c;
    #pragma unroll
    for (int k = 0; k < 4; ++k) c[k] = v[k] - mu;

    float q = c[0]*c[0] + c[1]*c[1] + c[2]*c[2] + c[3]*c[3];
    #pragma unroll
    for (int off = 32; off > 0; off >>= 1) q += __shfl_xor(q, off);
    const float rs = rsqrtf(q * (1.0f / DV) + LN_EPS);

    const f32x4 g  = ((const f32x4*)gamma)[ln];
    const f32x4 bt = ((const f32x4*)beta)[ln];

    half4 h;
    #pragma unroll
    for (int k = 0; k < 4; ++k) h[k] = (_Float16)(c[k] * rs * g[k] + bt[k]);
    out[row * 64 + ln] = h;
}

// ---------------- Kernel 2: barrier-free row phase: ONE WAVE = ONE ITEM ----------------
// 4096 blocks x 128 (2 independent waves/block; no __syncthreads anywhere).
// Wave-item: (b, lq) -> 4 l's, 64 edges (one per lane), 68 row-gathers, partial
// written straight to h_part[b][lq][*]. Waves free-run -> max latency overlap.
__global__ void __launch_bounds__(128) gnn_wave_kernel(
    const int*   __restrict__ nb_x,
    const int*   __restrict__ x,
    const float* __restrict__ we_flat,
    const float* __restrict__ eta_table,
    const half4* __restrict__ norm_emb,   // [VV*64]
    float*       __restrict__ h_part)     // [BB][NQ][DV]
{
    const int tid = threadIdx.x;
    const int ln  = tid & 63;
    const int wid = blockIdx.x * 2 + (tid >> 6);   // 0..8191 wave-items
    const int b   = wid >> 7;                      // batch
    const int lq  = wid & 127;                     // l-quad

    const int l0   = lq * LPW;
    const int base = b * LL + l0;

    // coalesced metadata + eta (per-lane; lanes 0-3 only for x/eta)
    const int   nbv = __builtin_nontemporal_load(nb_x    + base * DEG2 + ln);
    const float wev = __builtin_nontemporal_load(we_flat + base * DEG2 + ln);

    int xv = 0; float etv = 0.0f;
    if (ln < LPW) { xv = x[base + ln]; etv = eta_table[xv]; }

    f32x4 acc = {0.0f, 0.0f, 0.0f, 0.0f};

    #pragma unroll
    for (int li = 0; li < LPW; ++li) {
        half4 m;
        m[0] = m[1] = m[2] = m[3] = (_Float16)(-65504.0f);

        #pragma unroll
        for (int j = 0; j < DEG2; ++j) {
            const int   lane = li * DEG2 + j;          // compile-time lane -> readlane
            const int   idx  = __shfl(nbv, lane);
            const float wej  = __shfl(wev, lane);
            half4 w4; w4[0] = w4[1] = w4[2] = w4[3] = (_Float16)wej;
            const half4 e = norm_emb[idx * 64 + ln];
            m = __builtin_elementwise_max(m, w4 * e);  // pk_mul + pk_max
        }

        const int   sidx = __shfl(xv, li);
        const float eta  = __shfl(etv, li);
        const half4 se   = norm_emb[sidx * 64 + ln];
        const float om   = 1.0f - eta;
        #pragma unroll
        for (int k = 0; k < 4; ++k)
            acc[k] += om * (float)m[k] + eta * (float)se[k];
    }

    // direct per-wave store: no LDS, no barrier, no atomics
    __builtin_nontemporal_store(acc,
        (f32x4*)(h_part + (size_t)(b * NQ + lq) * DV) + ln);
}

// ---------------- Kernel 3: reduce 128 partials per batch, then FC ----------------
__global__ void __launch_bounds__(256) fc_kernel(
    const float* __restrict__ h_part,   // [BB][NQ][DV]
    const float* __restrict__ fc_w,
    const float* __restrict__ fc_b,
    float*       __restrict__ out)
{
    const int b  = blockIdx.x;
    const int d  = threadIdx.x;
    const int w  = d >> 6;
    const int ln = d & 63;

    float h = 0.0f;
    #pragma unroll 8
    for (int lq = 0; lq < NQ; ++lq)
        h += h_part[(size_t)(b * NQ + lq) * DV + d];

    float p[CC];
    #pragma unroll
    for (int c = 0; c < CC; ++c) p[c] = h * fc_w[d * CC + c];

    #pragma unroll
    for (int c = 0; c < CC; ++c)
        #pragma unroll
        for (int off = 32; off > 0; off >>= 1) p[c] += __shfl_xor(p[c], off);

    __shared__ float s_red[4][CC];
    if (ln == 0) {
        #pragma unroll
        for (int c = 0; c < CC; ++c) s_red[w][c] = p[c];
    }
    __syncthreads();
    if (d < CC)
        out[b * CC + d] = s_red[0][d] + s_red[1][d] + s_red[2][d] + s_red[3][d] + fc_b[d];
}

extern "C" void kernel_launch(void* const* d_in, const int* in_sizes, int n_in,
                              void* d_out, int out_size, void* d_ws, size_t ws_size,
                              hipStream_t stream) {
    const int*   x        = (const int*)  d_in[0];
    const int*   nb_x     = (const int*)  d_in[1];
    const int*   w_edge   = (const int*)  d_in[2];
    const float* emb_w    = (const float*)d_in[3];
    const float* we_table = (const float*)d_in[4];
    const float* eta_tab  = (const float*)d_in[5];
    const float* ln_gamma = (const float*)d_in[6];
    const float* ln_beta  = (const float*)d_in[7];
    const float* fc_w     = (const float*)d_in[8];
    const float* fc_b     = (const float*)d_in[9];
    float* out = (float*)d_out;

    // workspace layout
    char* ws = (char*)d_ws;
    half4* norm_emb = (half4*)(ws);                      // 8000*64*8   = 4,096,000 B
    float* we_flat  = (float*)(ws + 4096000);            // 524288*4    = 2,097,152 B
    float* h_part   = (float*)(ws + 4096000 + 2097152);  // 64*128*256*4 = 8,388,608 B

    ln_rows_kernel<<<VV, 64, 0, stream>>>(emb_w, ln_gamma, ln_beta,
                                          w_edge, we_table, norm_emb, we_flat);

    gnn_wave_kernel<<<BB * NQ / 2, 128, 0, stream>>>(
        nb_x, x, we_flat, eta_tab, norm_emb, h_part);

    fc_kernel<<<BB, 256, 0, stream>>>(h_part, fc_w, fc_b, out);
}

// Round 17
// 42.259 us; speedup vs baseline: 1.1723x; 1.1723x over previous
//
#include <hip/hip_runtime.h>
#include <math.h>

#define DV   256      // d_model
#define BB   64       // batch
#define LL   512      // seq len
#define DEG2 16       // 2 * n_degree
#define VV   8000     // vocab
#define CC   4        // n_category
#define LPW  4        // l's per wave
#define NW   4        // waves per block
#define NLC  32       // L-chunks (16 l per block)
#define NE   (BB*LL*DEG2)   // 524288 edges
#define LN_EPS 1e-5f

typedef _Float16 half4 __attribute__((ext_vector_type(4)));
typedef float    f32x4 __attribute__((ext_vector_type(4)));

// ---------------- Kernel A: LN table -> fp16, + we_flat gather, + out init ----------------
__global__ void __launch_bounds__(64) ln_rows_kernel(
    const float* __restrict__ emb, const float* __restrict__ gamma,
    const float* __restrict__ beta,
    const int* __restrict__ w_edge, const float* __restrict__ we_table,
    const float* __restrict__ fc_b,
    half4* __restrict__ out_tab, float* __restrict__ we_flat,
    float* __restrict__ out)
{
    const int row = blockIdx.x;
    const int ln  = threadIdx.x;

    // init out = fc_b broadcast (block 0 only; runs before gnn's atomics, same stream)
    if (row == 0) {
        #pragma unroll
        for (int i = ln; i < BB * CC; i += 64) out[i] = fc_b[i & 3];
    }

    // random we_table gather amortized across the grid (latency hides under LN)
    for (int g = blockIdx.x * 64 + ln; g < NE; g += VV * 64)
        we_flat[g] = we_table[w_edge[g]];

    const f32x4 v = ((const f32x4*)(emb + row * DV))[ln];

    float s = v[0] + v[1] + v[2] + v[3];
    #pragma unroll
    for (int off = 32; off > 0; off >>= 1) s += __shfl_xor(s, off);
    const float mu = s * (1.0f / DV);

    f32x4 c;
    #pragma unroll
    for (int k = 0; k < 4; ++k) c[k] = v[k] - mu;

    float q = c[0]*c[0] + c[1]*c[1] + c[2]*c[2] + c[3]*c[3];
    #pragma unroll
    for (int off = 32; off > 0; off >>= 1) q += __shfl_xor(q, off);
    const float rs = rsqrtf(q * (1.0f / DV) + LN_EPS);

    const f32x4 g  = ((const f32x4*)gamma)[ln];
    const f32x4 bt = ((const f32x4*)beta)[ln];

    half4 h;
    #pragma unroll
    for (int k = 0; k < 4; ++k) h[k] = (_Float16)(c[k] * rs * g[k] + bt[k]);
    out_tab[row * 64 + ln] = h;
}

// ---------------- Kernel B: gather + max + blend + block FC + atomic scores ----------------
// block = (b, lc); 4 waves; wave owns 4 l's (= 64 edges, one per lane).
// After the LDS wave-reduce, wave 0 computes the block's partial FC scores
// (h . fc_w) and atomicAdds 4 floats into out[b*4+c]. No h_part, no 3rd kernel.
__global__ void __launch_bounds__(256) gnn_kernel(
    const int*   __restrict__ nb_x,
    const int*   __restrict__ x,
    const float* __restrict__ we_flat,
    const float* __restrict__ eta_table,
    const half4* __restrict__ norm_emb,   // [VV*64]
    const float* __restrict__ fc_w,       // [DV][CC]
    float*       __restrict__ out)        // [BB][CC] (pre-set to fc_b)
{
    const int b   = blockIdx.x;
    const int lc  = blockIdx.y;
    const int tid = threadIdx.x;
    const int w   = tid >> 6;
    const int ln  = tid & 63;

    const int l0   = lc * 16 + w * LPW;
    const int base = b * LL + l0;

    const int   nbv = __builtin_nontemporal_load(nb_x    + base * DEG2 + ln);
    const float wev = __builtin_nontemporal_load(we_flat + base * DEG2 + ln);

    int xv = 0; float etv = 0.0f;
    if (ln < LPW) { xv = x[base + ln]; etv = eta_table[xv]; }

    f32x4 acc = {0.0f, 0.0f, 0.0f, 0.0f};

    #pragma unroll
    for (int li = 0; li < LPW; ++li) {
        half4 m;
        m[0] = m[1] = m[2] = m[3] = (_Float16)(-65504.0f);

        #pragma unroll
        for (int j = 0; j < DEG2; ++j) {
            const int   lane = li * DEG2 + j;          // compile-time lane
            const int   idx  = __shfl(nbv, lane);
            const float wej  = __shfl(wev, lane);
            half4 w4; w4[0] = w4[1] = w4[2] = w4[3] = (_Float16)wej;
            const half4 e = norm_emb[idx * 64 + ln];
            m = __builtin_elementwise_max(m, w4 * e);  // pk_mul + pk_max
        }

        const int   sidx = __shfl(xv, li);
        const float eta  = __shfl(etv, li);
        const half4 se   = norm_emb[sidx * 64 + ln];
        const float om   = 1.0f - eta;
        #pragma unroll
        for (int k = 0; k < 4; ++k)
            acc[k] += om * (float)m[k] + eta * (float)se[k];
    }

    // ---- block reduce across the 4 waves ----
    __shared__ float s_acc[NW][DV];
    ((f32x4*)s_acc[w])[ln] = acc;
    __syncthreads();
    if (w == 0) {
        f32x4 r0 = ((f32x4*)s_acc[0])[ln];
        f32x4 r1 = ((f32x4*)s_acc[1])[ln];
        f32x4 r2 = ((f32x4*)s_acc[2])[ln];
        f32x4 r3 = ((f32x4*)s_acc[3])[ln];
        f32x4 h;
        #pragma unroll
        for (int k = 0; k < 4; ++k) h[k] = r0[k] + r1[k] + r2[k] + r3[k];

        // ---- block-local FC: p[c] = sum_d h[d] * fc_w[d][c], d = 4*ln+k ----
        const f32x4 w0 = ((const f32x4*)fc_w)[ln * 4 + 0];  // fc_w[4ln+0][0..3]
        const f32x4 w1 = ((const f32x4*)fc_w)[ln * 4 + 1];
        const f32x4 w2 = ((const f32x4*)fc_w)[ln * 4 + 2];
        const f32x4 w3 = ((const f32x4*)fc_w)[ln * 4 + 3];

        float p[CC];
        #pragma unroll
        for (int c = 0; c < CC; ++c)
            p[c] = h[0] * w0[c] + h[1] * w1[c] + h[2] * w2[c] + h[3] * w3[c];

        #pragma unroll
        for (int c = 0; c < CC; ++c)
            #pragma unroll
            for (int off = 32; off > 0; off >>= 1) p[c] += __shfl_xor(p[c], off);

        if (ln == 0) {
            #pragma unroll
            for (int c = 0; c < CC; ++c)
                atomicAdd(&out[b * CC + c], p[c]);
        }
    }
}

extern "C" void kernel_launch(void* const* d_in, const int* in_sizes, int n_in,
                              void* d_out, int out_size, void* d_ws, size_t ws_size,
                              hipStream_t stream) {
    const int*   x        = (const int*)  d_in[0];
    const int*   nb_x     = (const int*)  d_in[1];
    const int*   w_edge   = (const int*)  d_in[2];
    const float* emb_w    = (const float*)d_in[3];
    const float* we_table = (const float*)d_in[4];
    const float* eta_tab  = (const float*)d_in[5];
    const float* ln_gamma = (const float*)d_in[6];
    const float* ln_beta  = (const float*)d_in[7];
    const float* fc_w     = (const float*)d_in[8];
    const float* fc_b     = (const float*)d_in[9];
    float* out = (float*)d_out;

    // workspace layout
    char* ws = (char*)d_ws;
    half4* norm_emb = (half4*)(ws);                      // 8000*64*8 = 4,096,000 B
    float* we_flat  = (float*)(ws + 4096000);            // 524288*4  = 2,097,152 B

    ln_rows_kernel<<<VV, 64, 0, stream>>>(emb_w, ln_gamma, ln_beta,
                                          w_edge, we_table, fc_b,
                                          norm_emb, we_flat, out);

    dim3 grid2(BB, NLC);
    gnn_kernel<<<grid2, 256, 0, stream>>>(nb_x, x, we_flat, eta_tab,
                                          norm_emb, fc_w, out);
}

// Round 18
// 41.468 us; speedup vs baseline: 1.1946x; 1.0191x over previous
//
#include <hip/hip_runtime.h>
#include <math.h>

#define DV   256      // d_model
#define BB   64       // batch
#define LL   512      // seq len
#define DEG2 16       // 2 * n_degree
#define VV   8000     // vocab
#define CC   4        // n_category
#define LPW  4        // l's per wave
#define NW   4        // waves per block
#define NLC  32       // L-chunks (16 l per block)
#define NE   (BB*LL*DEG2)   // 524288 edges
#define LN_EPS 1e-5f

typedef _Float16 half4 __attribute__((ext_vector_type(4)));
typedef float    f32x4 __attribute__((ext_vector_type(4)));

// ---------------- Kernel A: LN table -> fp16 + we_flat gather + out init ----------------
// 2000 blocks x 256 threads; wave r of block handles row blk*4+r.
__global__ void __launch_bounds__(256) ln_rows_kernel(
    const float* __restrict__ emb, const float* __restrict__ gamma,
    const float* __restrict__ beta,
    const int* __restrict__ w_edge, const float* __restrict__ we_table,
    const float* __restrict__ fc_b,
    half4* __restrict__ out_tab, float* __restrict__ we_flat,
    float* __restrict__ out)
{
    const int tid = threadIdx.x;
    const int w   = tid >> 6;
    const int ln  = tid & 63;
    const int row = blockIdx.x * 4 + w;

    // init out = fc_b broadcast (block 0; same stream, runs before gnn's atomics)
    if (blockIdx.x == 0 && tid < BB * CC) out[tid] = fc_b[tid & 3];

    // random we_table gather spread over all 512000 threads (hides under LN)
    for (int g = blockIdx.x * 256 + tid; g < NE; g += 2000 * 256)
        we_flat[g] = we_table[w_edge[g]];

    const f32x4 v = ((const f32x4*)(emb + row * DV))[ln];

    float s = v[0] + v[1] + v[2] + v[3];
    #pragma unroll
    for (int off = 32; off > 0; off >>= 1) s += __shfl_xor(s, off);
    const float mu = s * (1.0f / DV);

    f32x4 c;
    #pragma unroll
    for (int k = 0; k < 4; ++k) c[k] = v[k] - mu;

    float q = c[0]*c[0] + c[1]*c[1] + c[2]*c[2] + c[3]*c[3];
    #pragma unroll
    for (int off = 32; off > 0; off >>= 1) q += __shfl_xor(q, off);
    const float rs = rsqrtf(q * (1.0f / DV) + LN_EPS);

    const f32x4 g  = ((const f32x4*)gamma)[ln];
    const f32x4 bt = ((const f32x4*)beta)[ln];

    half4 h;
    #pragma unroll
    for (int k = 0; k < 4; ++k) h[k] = (_Float16)(c[k] * rs * g[k] + bt[k]);
    out_tab[row * 64 + ln] = h;
}

// ---------------- Kernel B: gather+max+blend+FC; ALL metadata via scalar s_load ----------------
// block = (b, lc); 4 waves; wave owns 4 l's. Wave-uniform addressing (readfirstlane)
// turns nb_x / we_flat / x / eta_table reads into SGPR loads through the constant
// cache: zero shuffles, zero vector metadata loads. The vector-memory queue carries
// ONLY the 68 norm_emb row loads per item.
__global__ void __launch_bounds__(256) gnn_kernel(
    const int*   __restrict__ nb_x,
    const int*   __restrict__ x,
    const float* __restrict__ we_flat,
    const float* __restrict__ eta_table,
    const half4* __restrict__ norm_emb,   // [VV*64]
    const float* __restrict__ fc_w,       // [DV][CC]
    float*       __restrict__ out)        // [BB][CC] (pre-set to fc_b)
{
    const int b   = blockIdx.x;
    const int lc  = blockIdx.y;
    const int tid = threadIdx.x;
    const int w   = tid >> 6;
    const int ln  = tid & 63;

    const int wu   = __builtin_amdgcn_readfirstlane(w);   // SGPR wave id
    const int base = b * LL + lc * 16 + wu * LPW;         // wave-uniform
    const int eb   = base * DEG2;

    f32x4 acc = {0.0f, 0.0f, 0.0f, 0.0f};

    #pragma unroll
    for (int li = 0; li < LPW; ++li) {
        // wave-uniform scalar metadata (s_load / constant cache)
        const int   sidx = x[base + li];
        const float eta  = eta_table[sidx];

        half4 m;
        m[0] = m[1] = m[2] = m[3] = (_Float16)(-65504.0f);

        #pragma unroll
        for (int j = 0; j < DEG2; ++j) {
            const int   idx = nb_x   [eb + li * DEG2 + j];   // SGPR
            const float wj  = we_flat[eb + li * DEG2 + j];   // SGPR
            half4 w4; w4[0] = w4[1] = w4[2] = w4[3] = (_Float16)wj;
            const half4 e = norm_emb[idx * 64 + ln];         // the only vector load
            m = __builtin_elementwise_max(m, w4 * e);        // pk_mul + pk_max
        }

        const half4 se = norm_emb[sidx * 64 + ln];
        const float om = 1.0f - eta;
        #pragma unroll
        for (int k = 0; k < 4; ++k)
            acc[k] += om * (float)m[k] + eta * (float)se[k];
    }

    // ---- block reduce across the 4 waves ----
    __shared__ float s_acc[NW][DV];
    ((f32x4*)s_acc[w])[ln] = acc;
    __syncthreads();
    if (w == 0) {
        f32x4 r0 = ((f32x4*)s_acc[0])[ln];
        f32x4 r1 = ((f32x4*)s_acc[1])[ln];
        f32x4 r2 = ((f32x4*)s_acc[2])[ln];
        f32x4 r3 = ((f32x4*)s_acc[3])[ln];
        f32x4 h;
        #pragma unroll
        for (int k = 0; k < 4; ++k) h[k] = r0[k] + r1[k] + r2[k] + r3[k];

        // block-local FC: p[c] = sum_d h[d] * fc_w[d][c], d = 4*ln+k
        const f32x4 w0 = ((const f32x4*)fc_w)[ln * 4 + 0];
        const f32x4 w1 = ((const f32x4*)fc_w)[ln * 4 + 1];
        const f32x4 w2 = ((const f32x4*)fc_w)[ln * 4 + 2];
        const f32x4 w3 = ((const f32x4*)fc_w)[ln * 4 + 3];

        float p[CC];
        #pragma unroll
        for (int c = 0; c < CC; ++c)
            p[c] = h[0] * w0[c] + h[1] * w1[c] + h[2] * w2[c] + h[3] * w3[c];

        #pragma unroll
        for (int c = 0; c < CC; ++c)
            #pragma unroll
            for (int off = 32; off > 0; off >>= 1) p[c] += __shfl_xor(p[c], off);

        if (ln == 0) {
            #pragma unroll
            for (int c = 0; c < CC; ++c)
                atomicAdd(&out[b * CC + c], p[c]);
        }
    }
}

extern "C" void kernel_launch(void* const* d_in, const int* in_sizes, int n_in,
                              void* d_out, int out_size, void* d_ws, size_t ws_size,
                              hipStream_t stream) {
    const int*   x        = (const int*)  d_in[0];
    const int*   nb_x     = (const int*)  d_in[1];
    const int*   w_edge   = (const int*)  d_in[2];
    const float* emb_w    = (const float*)d_in[3];
    const float* we_table = (const float*)d_in[4];
    const float* eta_tab  = (const float*)d_in[5];
    const float* ln_gamma = (const float*)d_in[6];
    const float* ln_beta  = (const float*)d_in[7];
    const float* fc_w     = (const float*)d_in[8];
    const float* fc_b     = (const float*)d_in[9];
    float* out = (float*)d_out;

    // workspace layout
    char* ws = (char*)d_ws;
    half4* norm_emb = (half4*)(ws);                      // 8000*64*8 = 4,096,000 B
    float* we_flat  = (float*)(ws + 4096000);            // 524288*4  = 2,097,152 B

    ln_rows_kernel<<<2000, 256, 0, stream>>>(emb_w, ln_gamma, ln_beta,
                                             w_edge, we_table, fc_b,
                                             norm_emb, we_flat, out);

    dim3 grid2(BB, NLC);
    gnn_kernel<<<grid2, 256, 0, stream>>>(nb_x, x, we_flat, eta_tab,
                                          norm_emb, fc_w, out);
}

// Round 19
// 41.202 us; speedup vs baseline: 1.2023x; 1.0064x over previous
//
#include <hip/hip_runtime.h>
#include <math.h>

#define DV   256      // d_model
#define BB   64       // batch
#define LL   512      // seq len
#define DEG2 16       // 2 * n_degree
#define VV   8000     // vocab
#define CC   4        // n_category
#define LPW  4        // l's per wave
#define NW   4        // waves per block
#define NLC  32       // L-chunks (16 l per block)
#define NE   (BB*LL*DEG2)   // 524288 edges
#define LN_EPS 1e-5f

typedef _Float16 half4 __attribute__((ext_vector_type(4)));
typedef float    f32x4 __attribute__((ext_vector_type(4)));

// ---------------- Kernel A: LN table -> fp16 + we_flat gather + out init ----------------
// 2000 blocks x 256; wave r handles row blk*4+r. Single-pass mean/var:
// one butterfly reduces {sum, sumsq} together -> half the reduction latency.
__global__ void __launch_bounds__(256) ln_rows_kernel(
    const float* __restrict__ emb, const float* __restrict__ gamma,
    const float* __restrict__ beta,
    const int* __restrict__ w_edge, const float* __restrict__ we_table,
    const float* __restrict__ fc_b,
    half4* __restrict__ out_tab, float* __restrict__ we_flat,
    float* __restrict__ out)
{
    const int tid = threadIdx.x;
    const int w   = tid >> 6;
    const int ln  = tid & 63;
    const int row = blockIdx.x * 4 + w;

    // init out = fc_b broadcast (block 0; same stream, runs before gnn's atomics)
    if (blockIdx.x == 0 && tid < BB * CC) out[tid] = fc_b[tid & 3];

    // random we_table gather spread over all 512000 threads (hides under LN)
    for (int g = blockIdx.x * 256 + tid; g < NE; g += 2000 * 256)
        we_flat[g] = we_table[w_edge[g]];

    const f32x4 v = ((const f32x4*)(emb + row * DV))[ln];

    float s = v[0] + v[1] + v[2] + v[3];
    float q = v[0]*v[0] + v[1]*v[1] + v[2]*v[2] + v[3]*v[3];
    #pragma unroll
    for (int off = 32; off > 0; off >>= 1) {
        s += __shfl_xor(s, off);
        q += __shfl_xor(q, off);
    }
    const float mu = s * (1.0f / DV);
    const float rs = rsqrtf(fmaxf(q * (1.0f / DV) - mu * mu, 0.0f) + LN_EPS);

    const f32x4 g  = ((const f32x4*)gamma)[ln];
    const f32x4 bt = ((const f32x4*)beta)[ln];

    half4 h;
    #pragma unroll
    for (int k = 0; k < 4; ++k) h[k] = (_Float16)((v[k] - mu) * rs * g[k] + bt[k]);
    out_tab[row * 64 + ln] = h;
}

// ---------------- Kernel B: gather+max+blend+FC; scalar metadata; early self loads ----------------
__global__ void __launch_bounds__(256) gnn_kernel(
    const int*   __restrict__ nb_x,
    const int*   __restrict__ x,
    const float* __restrict__ we_flat,
    const float* __restrict__ eta_table,
    const half4* __restrict__ norm_emb,   // [VV*64]
    const float* __restrict__ fc_w,       // [DV][CC]
    float*       __restrict__ out)        // [BB][CC] (pre-set to fc_b)
{
    const int b   = blockIdx.x;
    const int lc  = blockIdx.y;
    const int tid = threadIdx.x;
    const int w   = tid >> 6;
    const int ln  = tid & 63;

    const int wu   = __builtin_amdgcn_readfirstlane(w);   // SGPR wave id
    const int base = b * LL + lc * 16 + wu * LPW;         // wave-uniform
    const int eb   = base * DEG2;

    // ---- issue ALL self rows + eta scalars up front (overlap with neighbor loads) ----
    int   sidx[LPW];
    float eta [LPW];
    half4 se  [LPW];
    #pragma unroll
    for (int li = 0; li < LPW; ++li) {
        sidx[li] = x[base + li];                // s_load
        eta [li] = eta_table[sidx[li]];         // s_load
        se  [li] = norm_emb[sidx[li] * 64 + ln];
    }

    f32x4 acc = {0.0f, 0.0f, 0.0f, 0.0f};

    #pragma unroll
    for (int li = 0; li < LPW; ++li) {
        half4 m;
        m[0] = m[1] = m[2] = m[3] = (_Float16)(-65504.0f);

        #pragma unroll
        for (int j = 0; j < DEG2; ++j) {
            const int   idx = nb_x   [eb + li * DEG2 + j];   // SGPR
            const float wj  = we_flat[eb + li * DEG2 + j];   // SGPR
            half4 w4; w4[0] = w4[1] = w4[2] = w4[3] = (_Float16)wj;
            const half4 e = norm_emb[idx * 64 + ln];         // the only vector load
            m = __builtin_elementwise_max(m, w4 * e);        // pk_mul + pk_max
        }

        const float om = 1.0f - eta[li];
        #pragma unroll
        for (int k = 0; k < 4; ++k)
            acc[k] += om * (float)m[k] + eta[li] * (float)se[li][k];
    }

    // ---- block reduce across the 4 waves ----
    __shared__ float s_acc[NW][DV];
    ((f32x4*)s_acc[w])[ln] = acc;
    __syncthreads();
    if (w == 0) {
        f32x4 r0 = ((f32x4*)s_acc[0])[ln];
        f32x4 r1 = ((f32x4*)s_acc[1])[ln];
        f32x4 r2 = ((f32x4*)s_acc[2])[ln];
        f32x4 r3 = ((f32x4*)s_acc[3])[ln];
        f32x4 h;
        #pragma unroll
        for (int k = 0; k < 4; ++k) h[k] = r0[k] + r1[k] + r2[k] + r3[k];

        // block-local FC: p[c] = sum_d h[d] * fc_w[d][c], d = 4*ln+k
        const f32x4 w0 = ((const f32x4*)fc_w)[ln * 4 + 0];
        const f32x4 w1 = ((const f32x4*)fc_w)[ln * 4 + 1];
        const f32x4 w2 = ((const f32x4*)fc_w)[ln * 4 + 2];
        const f32x4 w3 = ((const f32x4*)fc_w)[ln * 4 + 3];

        float p[CC];
        #pragma unroll
        for (int c = 0; c < CC; ++c)
            p[c] = h[0] * w0[c] + h[1] * w1[c] + h[2] * w2[c] + h[3] * w3[c];

        #pragma unroll
        for (int c = 0; c < CC; ++c)
            #pragma unroll
            for (int off = 32; off > 0; off >>= 1) p[c] += __shfl_xor(p[c], off);

        if (ln == 0) {
            #pragma unroll
            for (int c = 0; c < CC; ++c)
                atomicAdd(&out[b * CC + c], p[c]);
        }
    }
}

extern "C" void kernel_launch(void* const* d_in, const int* in_sizes, int n_in,
                              void* d_out, int out_size, void* d_ws, size_t ws_size,
                              hipStream_t stream) {
    const int*   x        = (const int*)  d_in[0];
    const int*   nb_x     = (const int*)  d_in[1];
    const int*   w_edge   = (const int*)  d_in[2];
    const float* emb_w    = (const float*)d_in[3];
    const float* we_table = (const float*)d_in[4];
    const float* eta_tab  = (const float*)d_in[5];
    const float* ln_gamma = (const float*)d_in[6];
    const float* ln_beta  = (const float*)d_in[7];
    const float* fc_w     = (const float*)d_in[8];
    const float* fc_b     = (const float*)d_in[9];
    float* out = (float*)d_out;

    // workspace layout
    char* ws = (char*)d_ws;
    half4* norm_emb = (half4*)(ws);                      // 8000*64*8 = 4,096,000 B
    float* we_flat  = (float*)(ws + 4096000);            // 524288*4  = 2,097,152 B

    ln_rows_kernel<<<2000, 256, 0, stream>>>(emb_w, ln_gamma, ln_beta,
                                             w_edge, we_table, fc_b,
                                             norm_emb, we_flat, out);

    dim3 grid2(BB, NLC);
    gnn_kernel<<<grid2, 256, 0, stream>>>(nb_x, x, we_flat, eta_tab,
                                          norm_emb, fc_w, out);
}